// Round 10
// baseline (607.958 us; speedup 1.0000x reference)
//
#include <hip/hip_runtime.h>
#include <hip/hip_bf16.h>

typedef unsigned short u16;
typedef __bf16 bf16x8 __attribute__((ext_vector_type(8)));
typedef float floatx4 __attribute__((ext_vector_type(4)));

__device__ __forceinline__ float bf2f_u(u16 u) {
    union { unsigned int i; float f; } x; x.i = ((unsigned int)u) << 16; return x.f;
}
__device__ __forceinline__ u16 f2bf_u(float f) {
    union { float f; unsigned int i; } x; x.f = f;
    unsigned int r = x.i + 0x7fffu + ((x.i >> 16) & 1u);   // RNE
    return (u16)(r >> 16);
}

// ---------------------------------------------------------------------------
// fp32 -> bf16 flat convert (x prep). 2048 elems/block.
__global__ __launch_bounds__(256) void tobf_k(const float* __restrict__ in,
                                              u16* __restrict__ out) {
    int i = (blockIdx.x * 256 + threadIdx.x) * 8;
    float4 v0 = *(const float4*)&in[i];
    float4 v1 = *(const float4*)&in[i + 4];
    u16 tmp[8] = {f2bf_u(v0.x), f2bf_u(v0.y), f2bf_u(v0.z), f2bf_u(v0.w),
                  f2bf_u(v1.x), f2bf_u(v1.y), f2bf_u(v1.z), f2bf_u(v1.w)};
    *(uint4*)&out[i] = *(const uint4*)tmp;
}

// ---------------------------------------------------------------------------
// Tiled transpose+convert: out_bf16[c][r] (ld=R) = in_f32[r][c] (ld=C).
__global__ __launch_bounds__(256) void transpose_bf_k(
    const float* __restrict__ in, u16* __restrict__ out,
    int R, int C, size_t inZ, size_t outZ)
{
    __shared__ u16 T[64][80];
    const float* ip = in + blockIdx.z * inZ;
    u16* op = out + blockIdx.z * outZ;
    const int r0 = blockIdx.y * 64, c0 = blockIdx.x * 64;
    const int t = threadIdx.x;
#pragma unroll
    for (int i = 0; i < 4; i++) {
        int c = t + i * 256;
        int rr = c >> 4, cc = (c & 15) * 4;
        float4 v = *(const float4*)&ip[(size_t)(r0 + rr) * C + c0 + cc];
        T[cc + 0][rr] = f2bf_u(v.x); T[cc + 1][rr] = f2bf_u(v.y);
        T[cc + 2][rr] = f2bf_u(v.z); T[cc + 3][rr] = f2bf_u(v.w);
    }
    __syncthreads();
#pragma unroll
    for (int i = 0; i < 2; i++) {
        int c = t + i * 256;
        int oc = c >> 3, k8 = (c & 7) * 8;
        uint4 v = *(const uint4*)&T[oc][k8];
        *(uint4*)&op[(size_t)(c0 + oc) * R + r0 + k8] = v;
    }
}

// ---------------------------------------------------------------------------
// Barrier-free "flatmm" GEMM: C[M,N] = A[M,K] @ Bt[N,K]^T, all bf16.
// MFMA fragments loaded DIRECTLY global -> VGPR (the fragment access pattern
// (row base+lr, col quad*8) covers 16 consecutive rows x 64 contiguous bytes
// = full cachelines). No LDS, no __syncthreads in the K-loop -> the compiler
// schedules loads with precise vmcnt and pipelines across iterations; no
// barrier vmcnt(0) drain (the r9 bottleneck at 1 block/CU).
// XCD swizzle: tile grid (gm x gn) in 8 rectangles (4 m-bands x 2 n-bands).
// mode 0: out_bf = qh scatter [B,H,S,Dh], val+bias
// mode 1: out[m,n]    = val + bias + bf2f(resid[m,n])   (fp32)
// mode 2: out_bf[m,n] = relu(val + bias)
// mode 3: out[m,n]   += val                             (fp32)
// mode 4: out_bf[m,n] = val + bias + bf2f(resid[m,n])
__global__ __launch_bounds__(256) void gemm_bt_k(
    const u16* __restrict__ A, const u16* __restrict__ Bt,
    int gm, int gn, int N, int K, int ldb,
    const float* __restrict__ bias, const u16* __restrict__ resid,
    float* __restrict__ out, u16* __restrict__ out_bf, int mode)
{
    const int id = blockIdx.x;
    const int xcd = id & 7, s = id >> 3;
    const int bandM = gm >> 2, bandN = gn >> 1;
    const int m0 = ((xcd >> 1) * bandM + (s % bandM)) * 128;
    const int n0 = ((xcd & 1) * bandN + (s / bandM)) * 128;

    const int t = threadIdx.x;
    const int wid = t >> 6, lane = t & 63;
    const int wm = (wid >> 1) * 64, wn = (wid & 1) * 64;
    const int lr = lane & 15, quad = lane >> 4;

    // per-lane fragment base pointers (advance by 32 each iter)
    const u16* Ap[4];
    const u16* Bp[4];
#pragma unroll
    for (int i = 0; i < 4; i++)
        Ap[i] = &A[(size_t)(m0 + wm + i * 16 + lr) * K + quad * 8];
#pragma unroll
    for (int j = 0; j < 4; j++)
        Bp[j] = &Bt[(size_t)(n0 + wn + j * 16 + lr) * ldb + quad * 8];

    floatx4 acc[4][4];
#pragma unroll
    for (int i = 0; i < 4; i++)
#pragma unroll
        for (int j = 0; j < 4; j++)
            acc[i][j] = (floatx4){0.f, 0.f, 0.f, 0.f};

#pragma unroll 2
    for (int k0 = 0; k0 < K; k0 += 32) {
        bf16x8 af[4], bfr[4];
#pragma unroll
        for (int i = 0; i < 4; i++) af[i] = *(const bf16x8*)(Ap[i] + k0);
#pragma unroll
        for (int j = 0; j < 4; j++) bfr[j] = *(const bf16x8*)(Bp[j] + k0);
#pragma unroll
        for (int i = 0; i < 4; i++)
#pragma unroll
            for (int j = 0; j < 4; j++)
                acc[i][j] = __builtin_amdgcn_mfma_f32_16x16x32_bf16(af[i], bfr[j], acc[i][j], 0, 0, 0);
    }

#pragma unroll
    for (int i = 0; i < 4; i++) {
#pragma unroll
        for (int j = 0; j < 4; j++) {
#pragma unroll
            for (int r = 0; r < 4; r++) {
                int grow = m0 + wm + i * 16 + quad * 4 + r;
                int gcol = n0 + wn + j * 16 + lr;
                float val = acc[i][j][r];
                if (bias) val += bias[gcol];
                if (mode == 0) {
                    int bb = grow >> 11, ss = grow & 2047;
                    int h = gcol >> 6, e = gcol & 63;
                    out_bf[(((size_t)bb * 16 + h) * 2048 + ss) * 64 + e] = f2bf_u(val);
                } else if (mode == 1) {
                    size_t idx = (size_t)grow * N + gcol;
                    out[idx] = val + bf2f_u(resid[idx]);
                } else if (mode == 2) {
                    out_bf[(size_t)grow * N + gcol] = f2bf_u(fmaxf(val, 0.f));
                } else if (mode == 3) {
                    size_t idx = (size_t)grow * N + gcol;
                    out[idx] = out[idx] + val;
                } else {  // mode 4
                    size_t idx = (size_t)grow * N + gcol;
                    out_bf[idx] = f2bf_u(val + bf2f_u(resid[idx]));
                }
            }
        }
    }
}

// ---------------------------------------------------------------------------
// MFMA flash attention v2 (proven round 8).
#define KST 72
#define PST 68
__global__ __launch_bounds__(256) void attn_mfma_k(const u16* __restrict__ qh,
                                                   u16* __restrict__ ctx)
{
    __shared__ __align__(16) u16 Ks[64][KST];
    __shared__ __align__(16) u16 Vt[64][KST];
    __shared__ __align__(16) u16 Ps[4][2][16][PST];

    const int bh = blockIdx.x >> 4;
    const int qb = blockIdx.x & 15;
    const u16* __restrict__ base = qh + (size_t)bh * (2048 * 64);
    const int t = threadIdx.x, wid = t >> 6, lane = t & 63;
    const int lr = lane & 15, quad = lane >> 4;
    const int q0 = qb * 128 + wid * 16;

    bf16x8 af[2][2];
#pragma unroll
    for (int f = 0; f < 2; f++) {
        af[f][0] = *(const bf16x8*)&base[(size_t)(q0 + f * 64 + lr) * 64 + quad * 8];
        af[f][1] = *(const bf16x8*)&base[(size_t)(q0 + f * 64 + lr) * 64 + quad * 8 + 32];
    }

    floatx4 Of[2][4];
#pragma unroll
    for (int f = 0; f < 2; f++)
#pragma unroll
        for (int dt = 0; dt < 4; dt++) Of[f][dt] = (floatx4){0.f, 0.f, 0.f, 0.f};
    float lsum[2][4] = {{0.f,0.f,0.f,0.f},{0.f,0.f,0.f,0.f}};

    for (int kt = 0; kt < 2048; kt += 64) {
        __syncthreads();
#pragma unroll
        for (int cc = 0; cc < 2; cc++) {
            int c = t + cc * 256;
            int row = c >> 3, col = (c & 7) * 8;
            uint4 v = *(const uint4*)&base[(size_t)(kt + row) * 64 + col];
            *(uint4*)&Ks[row][col] = v;
            const u16* pv = (const u16*)&v;
#pragma unroll
            for (int i = 0; i < 8; i++) {
                int d = col + i;
                Vt[d][row ^ (d & 0x38)] = pv[i];
            }
        }
        __syncthreads();

#pragma unroll
        for (int nt = 0; nt < 4; nt++) {
            bf16x8 b0 = *(const bf16x8*)&Ks[nt * 16 + lr][quad * 8];
            bf16x8 b1 = *(const bf16x8*)&Ks[nt * 16 + lr][quad * 8 + 32];
#pragma unroll
            for (int f = 0; f < 2; f++) {
                floatx4 z = (floatx4){0.f, 0.f, 0.f, 0.f};
                z = __builtin_amdgcn_mfma_f32_16x16x32_bf16(af[f][0], b0, z, 0, 0, 0);
                z = __builtin_amdgcn_mfma_f32_16x16x32_bf16(af[f][1], b1, z, 0, 0, 0);
#pragma unroll
                for (int r = 0; r < 4; r++) {
                    float p = __expf(fminf(z[r] * 0.125f, 60.f));
                    lsum[f][r] += p;
                    Ps[wid][f][quad * 4 + r][nt * 16 + lr] = f2bf_u(p);
                }
            }
        }

        bf16x8 aP[2][2];
#pragma unroll
        for (int f = 0; f < 2; f++) {
            aP[f][0] = *(const bf16x8*)&Ps[wid][f][lr][quad * 8];
            aP[f][1] = *(const bf16x8*)&Ps[wid][f][lr][quad * 8 + 32];
        }
#pragma unroll
        for (int dt = 0; dt < 4; dt++) {
            int d = dt * 16 + lr, msk = d & 0x38;
            bf16x8 b0 = *(const bf16x8*)&Vt[d][(quad * 8) ^ msk];
            bf16x8 b1 = *(const bf16x8*)&Vt[d][(32 + quad * 8) ^ msk];
#pragma unroll
            for (int f = 0; f < 2; f++) {
                Of[f][dt] = __builtin_amdgcn_mfma_f32_16x16x32_bf16(aP[f][0], b0, Of[f][dt], 0, 0, 0);
                Of[f][dt] = __builtin_amdgcn_mfma_f32_16x16x32_bf16(aP[f][1], b1, Of[f][dt], 0, 0, 0);
            }
        }
    }

    const int b = bh >> 4, h = bh & 15;
#pragma unroll
    for (int f = 0; f < 2; f++) {
#pragma unroll
        for (int r = 0; r < 4; r++) {
            float l = lsum[f][r];
#pragma unroll
            for (int off = 1; off < 16; off <<= 1) l += __shfl_xor(l, off);
            float inv = 1.f / l;
            size_t rowoff = ((size_t)b * 2048 + q0 + f * 64 + quad * 4 + r) * 1024 + h * 64;
#pragma unroll
            for (int dt = 0; dt < 4; dt++)
                ctx[rowoff + dt * 16 + lr] = f2bf_u(Of[f][dt][r] * inv);
        }
    }
}

// ---------------------------------------------------------------------------
// LayerNorm D=1024; input bf16 (icode 0) or fp32 (icode 1); out fp32/bf16.
__global__ __launch_bounds__(256) void ln_k(const void* __restrict__ in,
                                            const float* __restrict__ g,
                                            const float* __restrict__ b,
                                            float* __restrict__ out_f,
                                            u16* __restrict__ out_bf, int icode)
{
    const int row = blockIdx.x;
    const int t = threadIdx.x;
    float4 v;
    if (icode) {
        v = *(const float4*)&((const float*)in)[(size_t)row * 1024 + t * 4];
    } else {
        ushort4 u = *(const ushort4*)&((const u16*)in)[(size_t)row * 1024 + t * 4];
        v.x = bf2f_u(u.x); v.y = bf2f_u(u.y); v.z = bf2f_u(u.z); v.w = bf2f_u(u.w);
    }
    float s  = v.x + v.y + v.z + v.w;
    float ss = v.x * v.x + v.y * v.y + v.z * v.z + v.w * v.w;
#pragma unroll
    for (int off = 32; off >= 1; off >>= 1) {
        s  += __shfl_down(s, off);
        ss += __shfl_down(ss, off);
    }
    __shared__ float sm[10];
    const int wid = t >> 6, lane = t & 63;
    if (lane == 0) { sm[wid] = s; sm[4 + wid] = ss; }
    __syncthreads();
    if (t == 0) {
        float S  = sm[0] + sm[1] + sm[2] + sm[3];
        float SS = sm[4] + sm[5] + sm[6] + sm[7];
        float mu = S * (1.f / 1024.f);
        float var = SS * (1.f / 1024.f) - mu * mu;
        sm[8] = mu; sm[9] = rsqrtf(fmaxf(var, 0.f) + 1e-5f);
    }
    __syncthreads();
    float mu = sm[8], rs = sm[9];
    float4 G  = *(const float4*)&g[t * 4];
    float4 Bv = *(const float4*)&b[t * 4];
    float r0 = (v.x - mu) * rs * G.x + Bv.x;
    float r1 = (v.y - mu) * rs * G.y + Bv.y;
    float r2 = (v.z - mu) * rs * G.z + Bv.z;
    float r3 = (v.w - mu) * rs * G.w + Bv.w;
    if (out_f) {
        float4 ov = {r0, r1, r2, r3};
        *(float4*)&out_f[(size_t)row * 1024 + t * 4] = ov;
    }
    if (out_bf) {
        ushort4 ou = {f2bf_u(r0), f2bf_u(r1), f2bf_u(r2), f2bf_u(r3)};
        *(ushort4*)&out_bf[(size_t)row * 1024 + t * 4] = ou;
    }
}

// ---------------------------------------------------------------------------
extern "C" void kernel_launch(void* const* d_in, const int* in_sizes, int n_in,
                              void* d_out, int out_size, void* d_ws, size_t ws_size,
                              hipStream_t stream)
{
    const float* x    = (const float*)d_in[0];
    const float* wq_w = (const float*)d_in[1];
    const float* wq_b = (const float*)d_in[2];
    const float* fc_w = (const float*)d_in[3];
    const float* fc_b = (const float*)d_in[4];
    const float* ln1g = (const float*)d_in[5];
    const float* ln1b = (const float*)d_in[6];
    const float* w1   = (const float*)d_in[7];
    const float* b1   = (const float*)d_in[8];
    const float* w2   = (const float*)d_in[9];
    const float* b2   = (const float*)d_in[10];
    const float* ln2g = (const float*)d_in[11];
    const float* ln2b = (const float*)d_in[12];

    // Workspace (same proven layout as round 9):
    char* ws = (char*)d_ws;
    const size_t MB = 1024 * 1024;
    u16*   w1_bt  = (u16*)(ws);
    u16*   w2_bt  = (u16*)(ws + 8 * MB);
    u16*   wqm_bt = (u16*)(ws + 16 * MB);
    u16*   fcw_bt = (u16*)(ws + 18 * MB);
    u16*   x_bf   = (u16*)(ws + 20 * MB);
    u16*   qh     = (u16*)(ws + 28 * MB);
    u16*   yln1   = (u16*)(ws + 28 * MB);
    u16*   ctx    = (u16*)(ws + 36 * MB);
    u16*   yfc_bf = (u16*)(ws + 44 * MB);
    u16*   h1     = (u16*)(ws + 36 * MB);
    float* z      = (float*)d_out;
    const bool fullN = ws_size >= 69 * MB;

    // prep
    transpose_bf_k<<<dim3(64, 16), 256, 0, stream>>>(w1, w1_bt, 1024, 4096, 0, 0);
    transpose_bf_k<<<dim3(16, 64), 256, 0, stream>>>(w2, w2_bt, 4096, 1024, 0, 0);
    transpose_bf_k<<<dim3(1, 16, 16), 256, 0, stream>>>(wq_w, wqm_bt, 1024, 64,
                                                        (size_t)1024 * 64, (size_t)64 * 1024);
    transpose_bf_k<<<dim3(16, 16), 256, 0, stream>>>(fc_w, fcw_bt, 1024, 1024, 0, 0);
    tobf_k<<<2048, 256, 0, stream>>>(x, x_bf);

    // qproj: x_bf @ wqm_bt^T + wq_b -> qh scatter   (gm=32, gn=8)
    gemm_bt_k<<<256, 256, 0, stream>>>(x_bf, wqm_bt, 32, 8, 1024, 1024, 1024,
                                       wq_b, nullptr, nullptr, qh, 0);
    attn_mfma_k<<<512, 256, 0, stream>>>(qh, ctx);
    // fc: ctx @ fcw_bt^T + fc_b + x_bf -> yfc_bf    (gm=32, gn=8)
    gemm_bt_k<<<256, 256, 0, stream>>>(ctx, fcw_bt, 32, 8, 1024, 1024, 1024,
                                       fc_b, x_bf, nullptr, yfc_bf, 4);
    ln_k<<<4096, 256, 0, stream>>>(yfc_bf, ln1g, ln1b, nullptr, yln1, 0);

    if (fullN) {
        gemm_bt_k<<<1024, 256, 0, stream>>>(yln1, w1_bt, 32, 32, 4096, 1024, 1024,
                                            b1, nullptr, nullptr, h1, 2);
        gemm_bt_k<<<256, 256, 0, stream>>>(h1, w2_bt, 32, 8, 1024, 4096, 4096,
                                           b2, yln1, z, nullptr, 1);
    } else {
        gemm_bt_k<<<512, 256, 0, stream>>>(yln1, w1_bt, 32, 16, 2048, 1024, 1024,
                                           b1, nullptr, nullptr, h1, 2);
        gemm_bt_k<<<256, 256, 0, stream>>>(h1, w2_bt, 32, 8, 1024, 2048, 4096,
                                           b2, yln1, z, nullptr, 1);
        gemm_bt_k<<<512, 256, 0, stream>>>(yln1, w1_bt + (size_t)2048 * 1024, 32, 16,
                                           2048, 1024, 1024,
                                           b1 + 2048, nullptr, nullptr, h1, 2);
        gemm_bt_k<<<256, 256, 0, stream>>>(h1, w2_bt + 2048, 32, 8, 1024, 2048, 4096,
                                           nullptr, nullptr, z, nullptr, 3);
    }
    ln_k<<<4096, 256, 0, stream>>>(z, ln2g, ln2b, (float*)d_out, nullptr, 1);
}